// Round 8
// baseline (3797.755 us; speedup 1.0000x reference)
//
#include <hip/hip_runtime.h>
#include <hip/hip_fp16.h>
#include <math.h>

// ---------------------------------------------------------------------------
// RelationExtractionModel B=64,T=256. Round 8: BiLSTM with 8 blocks total
// (4 slices x 2 dirs, 64 units/slice, 128KB weights in VGPR B-fragments).
// Ownership remap (thread -> (b=tid>>2, 16 units)) gives register-direct
// coalesced publish, coalesced xW loads ([t][slice][gate][b][u] staging),
// 3-peer flags, own-slice-skipping gather. Rest unchanged from round 7.
// ---------------------------------------------------------------------------

typedef _Float16 f16x8 __attribute__((ext_vector_type(8)));
typedef float    f32x4 __attribute__((ext_vector_type(4)));

union PK2 { _Float16 h[16]; f16x8 v[2]; unsigned long long u64[4]; };

__device__ __forceinline__ float sigm(float x) { return 1.0f / (1.0f + expf(-x)); }

struct EmbArgs {
  const float* tf; const int* pos_ids; const int* dep_ids;
  const int* e1; const int* e2; const int* sdp;
  const float* pos_tab; const float* dep_tab; const float* dist_tab;
  const float* sdp_tab;
};

// ---------------- weight pack: BT[n*Kpad+k] = f16(W[k*N+n]) ----------------
__global__ __launch_bounds__(256) void k_packB(const float* __restrict__ W,
                                               __half* __restrict__ BT,
                                               int N, int Kpad) {
  int k = blockIdx.x;
  int n = blockIdx.y * 256 + threadIdx.x;
  BT[(size_t)n * Kpad + k] = __float2half_rn(W[(size_t)k * N + n]);
}
__global__ __launch_bounds__(256) void k_zft(__half* __restrict__ BT) {
  int i = blockIdx.x * 256 + threadIdx.x;  // 512 rows x 16 pad cols
  int n = i >> 4, kk = i & 15;
  BT[(size_t)n * 928 + 912 + kk] = __float2half_rn(0.0f);
}

// ---- LSTM weight pack (4 slices of 64 units):
// WB[(j*256 + c)*256 + k] = f16(Whh[k][ (c&3)*256 + j*64 + (c>>2) ])
__global__ __launch_bounds__(256) void k_packWB(const float* __restrict__ W,
                                                __half* __restrict__ WB) {
  int i = blockIdx.x * 256 + threadIdx.x;  // 0..262143
  int k = i & 255;
  int c = (i >> 8) & 255;
  int j = i >> 16;
  int col = (c & 3) * 256 + j * 64 + (c >> 2);
  WB[i] = __float2half_rn(W[(size_t)k * 1024 + col]);
}

// ---------------- zero the sync flags ----------------
__global__ __launch_bounds__(256) void k_zero(unsigned int* __restrict__ p,
                                              int n) {
  int i = blockIdx.x * 256 + threadIdx.x;
  if (i < n) p[i] = 0u;
}

// ---------------- MFMA f16 GEMM ----------------
// out_mode: 0 = f32 row-major, 1 = f16 row-major, 2 = f16 LSTM staging layout
// [t][slice4][gate4][b64][u64] (M must be 16384 rows = b*256+t, N=1024).
__global__ __launch_bounds__(256) void k_mgemm(
    const __half* __restrict__ A16, const __half* __restrict__ BT,
    const float* __restrict__ bias, void* __restrict__ out,
    int N, int K, int lda, int a_embed, int act_tanh, int out_mode,
    EmbArgs ea) {
  __shared__ _Float16 As[128 * 40];
  __shared__ _Float16 Bs[128 * 40];
  int tid = threadIdx.x;
  int lane = tid & 63, wave = tid >> 6;
  int wm = wave & 1, wn = wave >> 1;
  int col0 = blockIdx.x * 128, row0 = blockIdx.y * 128;

  f32x4 acc[4][4];
#pragma unroll
  for (int i = 0; i < 4; ++i)
#pragma unroll
    for (int j = 0; j < 4; ++j) acc[i][j] = (f32x4)0.0f;

  for (int kt = 0; kt < K; kt += 32) {
    __syncthreads();
#pragma unroll
    for (int it = 0; it < 2; ++it) {
      int lin = tid + it * 256;
      int r = lin & 127, kh8 = (lin >> 7) * 8;
      f16x8 va;
      if (!a_embed) {
        va = *(const f16x8*)(A16 + (size_t)(row0 + r) * lda + kt + kh8);
      } else {
        int row = row0 + r;
        int k0 = kt + kh8;
        if (k0 >= 912) {
          va = (f16x8)(_Float16)0.0f;
        } else {
          const float* src;
          if (k0 < 768) {
            src = ea.tf + (size_t)row * 768 + k0;
          } else {
            int b_ = row >> 8, t_ = row & 255;
            if (k0 < 800) src = ea.pos_tab + ea.pos_ids[row] * 32 + (k0 - 768);
            else if (k0 < 832) src = ea.dep_tab + ea.dep_ids[row] * 32 + (k0 - 800);
            else if (k0 < 864) {
              int d = t_ - ea.e1[b_] + 10; d = d < 0 ? 0 : (d > 20 ? 20 : d);
              src = ea.dist_tab + d * 32 + (k0 - 832);
            } else if (k0 < 896) {
              int d = t_ - ea.e2[b_] + 10; d = d < 0 ? 0 : (d > 20 ? 20 : d);
              src = ea.dist_tab + d * 32 + (k0 - 864);
            } else {
              src = ea.sdp_tab + ea.sdp[row] * 16 + (k0 - 896);
            }
          }
          float4 a = *(const float4*)src;
          float4 b2 = *(const float4*)(src + 4);
          va[0] = (_Float16)a.x;  va[1] = (_Float16)a.y;
          va[2] = (_Float16)a.z;  va[3] = (_Float16)a.w;
          va[4] = (_Float16)b2.x; va[5] = (_Float16)b2.y;
          va[6] = (_Float16)b2.z; va[7] = (_Float16)b2.w;
        }
      }
      *(f16x8*)&As[r * 40 + kh8] = va;
      f16x8 vb = *(const f16x8*)(BT + (size_t)(col0 + r) * K + kt + kh8);
      *(f16x8*)&Bs[r * 40 + kh8] = vb;
    }
    __syncthreads();
    f16x8 af[4], bf[4];
    int kq = (lane >> 4) * 8;
#pragma unroll
    for (int mt = 0; mt < 4; ++mt)
      af[mt] = *(const f16x8*)&As[(wm * 64 + mt * 16 + (lane & 15)) * 40 + kq];
#pragma unroll
    for (int nt = 0; nt < 4; ++nt)
      bf[nt] = *(const f16x8*)&Bs[(wn * 64 + nt * 16 + (lane & 15)) * 40 + kq];
#pragma unroll
    for (int mt = 0; mt < 4; ++mt)
#pragma unroll
      for (int nt = 0; nt < 4; ++nt)
        acc[mt][nt] = __builtin_amdgcn_mfma_f32_16x16x32_f16(
            af[mt], bf[nt], acc[mt][nt], 0, 0, 0);
  }

#pragma unroll
  for (int mt = 0; mt < 4; ++mt) {
#pragma unroll
    for (int nt = 0; nt < 4; ++nt) {
      int col = col0 + wn * 64 + nt * 16 + (lane & 15);
      float bv = bias[col];
#pragma unroll
      for (int r = 0; r < 4; ++r) {
        int row = row0 + wm * 64 + mt * 16 + (lane >> 4) * 4 + r;
        float v = acc[mt][nt][r] + bv;
        if (act_tanh) v = tanhf(v);
        if (out_mode == 0) {
          ((float*)out)[(size_t)row * N + col] = v;
        } else if (out_mode == 1) {
          ((__half*)out)[(size_t)row * N + col] = __float2half_rn(v);
        } else {
          // LSTM staging: [t][slice4][gate4][b][64 units]
          int b_ = row >> 8, t_ = row & 255;
          int g_ = col >> 8, u_ = col & 255;
          int sl = u_ >> 6, ul = u_ & 63;
          ((__half*)out)[(((size_t)(t_ * 4 + sl) * 4 + g_) * 64 + b_) * 64 + ul] =
              __float2half_rn(v);
        }
      }
    }
  }
}

// ---------------- BiLSTM v4: 8 blocks = 2 dirs x 4 unit-slices ------------
// 64 units/slice in VGPR B-fragments (128 VGPRs). Thread tid owns batch
// b=tid>>2, units (tid&3)*16. Register-direct coalesced publish, 3-peer
// store-flags, own-slice-skipping coalesced gather with normal loads.
__global__ __launch_bounds__(256, 1) void k_lstm3(
    const __half* __restrict__ XFs, const __half* __restrict__ XBs,
    const __half* __restrict__ WBf, const __half* __restrict__ WBb,
    __half* __restrict__ HexS, unsigned int* __restrict__ flags,
    __half* __restrict__ XT) {
  int bx = blockIdx.x;          // 0..7
  int dir = bx >> 2, slice = bx & 3;
  int tid = threadIdx.x;
  int lane = tid & 63, wave = tid >> 6;
  const __half* xWs = dir ? XBs : XFs;
  const __half* WB = dir ? WBb : WBf;
  __half* hexd = HexS + (size_t)dir * 256 * 16384;  // [step][slice4][b64][u64]
  unsigned int* flg = flags + dir * 1024;           // [slice][step]

  __shared__ _Float16 H[64 * 266];   // [b][u], row stride 266 f16
  __shared__ float GT[64 * 261];     // [b][c], row stride 261 dw (c=ul*4+g)

  // ---- preload B-fragments (resident all 256 steps): 256 cols x 256 k
  f16x8 bfrag[4][8];
#pragma unroll
  for (int nt2 = 0; nt2 < 4; ++nt2) {
    int c = (wave * 4 + nt2) * 16 + (lane & 15);
#pragma unroll
    for (int kt = 0; kt < 8; ++kt)
      bfrag[nt2][kt] = *(const f16x8*)(
          WB + ((size_t)(slice * 256 + c) * 256) + kt * 32 + (lane >> 4) * 8);
  }
  // ---- zero H
  for (int i = tid; i < 64 * 266 / 8; i += 256)
    ((f16x8*)H)[i] = (f16x8)(_Float16)0.0f;
  float cst[16];
#pragma unroll
  for (int p = 0; p < 16; ++p) cst[p] = 0.0f;
  int b_own = tid >> 2;
  int ug = (tid & 3) * 16;
  __syncthreads();

  for (int s = 0; s < 256; ++s) {
    int t = dir ? (255 - s) : s;

    // ---- MFMA: gates[64 b, 256 c] = H[64,256] @ Wslice[256,256]
    f32x4 acc[4][4];
#pragma unroll
    for (int mt = 0; mt < 4; ++mt)
#pragma unroll
      for (int nt2 = 0; nt2 < 4; ++nt2) acc[mt][nt2] = (f32x4)0.0f;
#pragma unroll
    for (int kt = 0; kt < 8; ++kt) {
      f16x8 a[4];
#pragma unroll
      for (int mt = 0; mt < 4; ++mt)
        a[mt] = *(const f16x8*)&H[(mt * 16 + (lane & 15)) * 266 + kt * 32 +
                                  (lane >> 4) * 8];
#pragma unroll
      for (int mt = 0; mt < 4; ++mt)
#pragma unroll
        for (int nt2 = 0; nt2 < 4; ++nt2)
          acc[mt][nt2] = __builtin_amdgcn_mfma_f32_16x16x32_f16(
              a[mt], bfrag[nt2][kt], acc[mt][nt2], 0, 0, 0);
    }
    __syncthreads();  // H consumed; GT fully read by all (prev update)
    // ---- transpose C-layout -> GT[b][c]
#pragma unroll
    for (int mt = 0; mt < 4; ++mt)
#pragma unroll
      for (int nt2 = 0; nt2 < 4; ++nt2) {
        int col = (wave * 4 + nt2) * 16 + (lane & 15);
#pragma unroll
        for (int r = 0; r < 4; ++r) {
          int b = mt * 16 + (lane >> 4) * 4 + r;
          GT[b * 261 + col] = acc[mt][nt2][r];
        }
      }
    __syncthreads();
    // ---- c/h update for own (b_own, units ug..ug+15)
    PK2 hv;
    const __half* xwp =
        xWs + ((((size_t)(t * 4 + slice) * 4) * 64 + b_own) * 64) + ug;
#pragma unroll
    for (int p8 = 0; p8 < 2; ++p8) {
      f16x8 xg[4];
#pragma unroll
      for (int g = 0; g < 4; ++g)
        xg[g] = *(const f16x8*)(xwp + g * 4096 + p8 * 8);
#pragma unroll
      for (int p = 0; p < 8; ++p) {
        int ul = ug + p8 * 8 + p;
        float4 g4 = *(const float4*)&GT[b_own * 261 + 4 * ul];
        float gi = g4.x + (float)xg[0][p];
        float gf = g4.y + (float)xg[1][p];
        float gg = g4.z + (float)xg[2][p];
        float go = g4.w + (float)xg[3][p];
        int pc = p8 * 8 + p;
        cst[pc] = sigm(gf) * cst[pc] + sigm(gi) * tanhf(gg);
        float hn = sigm(go) * tanhf(cst[pc]);
        hv.h[pc] = (_Float16)hn;
      }
    }
    // own h -> LDS H
    *(f16x8*)&H[b_own * 266 + slice * 64 + ug] = hv.v[0];
    *(f16x8*)&H[b_own * 266 + slice * 64 + ug + 8] = hv.v[1];

    if (s < 255) {
      __half* hexq = hexd + (size_t)s * 16384;
      // ---- publish directly from registers (wave-contiguous 32B/thread)
      unsigned long long* dst =
          (unsigned long long*)(hexq + slice * 4096 + tid * 16);
#pragma unroll
      for (int w = 0; w < 4; ++w)
        __hip_atomic_store(&dst[w], hv.u64[w], __ATOMIC_RELAXED,
                           __HIP_MEMORY_SCOPE_AGENT);
      // drain own wave's publish stores to the LLC, then block rendezvous
      asm volatile("s_waitcnt vmcnt(0)" ::: "memory");
      __syncthreads();
      if (tid == 0)
        __hip_atomic_store(&flg[(slice << 8) + s], 1u, __ATOMIC_RELAXED,
                           __HIP_MEMORY_SCOPE_AGENT);
      // XT stores AFTER flag (out of the drain path)
      {
        __half* xt = XT + (size_t)((b_own << 8) + t) * 544 + dir * 256 +
                     slice * 64 + ug;
        *(f16x8*)xt = hv.v[0];
        *(f16x8*)(xt + 8) = hv.v[1];
      }
      // poll the 3 peer flags in parallel (lanes 0..3)
      if (tid < 4 && tid != slice) {
        while (__hip_atomic_load(&flg[(tid << 8) + s], __ATOMIC_RELAXED,
                                 __HIP_MEMORY_SCOPE_AGENT) == 0u)
          __builtin_amdgcn_s_sleep(1);
      }
      __syncthreads();
      // ---- gather 3 peer slices with NORMAL loads (step-unique, LLC-resident)
#pragma unroll
      for (int i = 0; i < 6; ++i) {
        int idx = i * 256 + tid;          // [3 peers][64 b][8 chunks of 8u]
        int j3 = idx >> 9;
        int within = idx & 511;
        int ps = j3 + (j3 >= slice ? 1 : 0);
        int b = within >> 3, uc = within & 7;
        f16x8 pv = *(const f16x8*)(hexq + ps * 4096 + (b << 6) + uc * 8);
        *(f16x8*)&H[b * 266 + ps * 64 + uc * 8] = pv;
      }
      __syncthreads();  // H complete before next step's MFMA
    } else {
      __half* xt = XT + (size_t)((b_own << 8) + t) * 544 + dir * 256 +
                   slice * 64 + ug;
      *(f16x8*)xt = hv.v[0];
      *(f16x8*)(xt + 8) = hv.v[1];
    }
  }
}

// ---------------- fill dep_emb into x_tree cols [512,544), f16 -------------
__global__ __launch_bounds__(256) void k_depfill(
    const int* __restrict__ dep_ids, const float* __restrict__ dep_tab,
    __half* __restrict__ XT) {
  int e = blockIdx.x * 256 + threadIdx.x;  // 0..524287
  int row = e >> 5, k = e & 31;
  XT[(size_t)row * 544 + 512 + k] = __float2half_rn(dep_tab[dep_ids[row] * 32 + k]);
}

// ---------------- fp32 VALU GEMM (tree stages only) ----------------
__global__ __launch_bounds__(256) void k_gemm(
    const float* __restrict__ A, const float* __restrict__ Bm,
    const float* __restrict__ bias, void* __restrict__ Cv,
    int M, int N, int K, int lda,
    int a_mode, int band_lo, int band_log2,
    int epi_mode,
    const int* __restrict__ dep_heads,
    const float* __restrict__ xWf, const float* __restrict__ c_buf) {
  __shared__ float As[16][132];
  __shared__ float Bs[16][132];
  int tid = threadIdx.x;
  int col0 = blockIdx.x * 128;
  int row0 = blockIdx.y * 128;
  int tx = tid & 15, ty = tid >> 4;
  float acc[8][8];
#pragma unroll
  for (int i = 0; i < 8; ++i)
#pragma unroll
    for (int j = 0; j < 8; ++j) acc[i][j] = 0.0f;

  int bmask = (1 << band_log2) - 1;
  for (int kt = 0; kt < K; kt += 16) {
#pragma unroll
    for (int i = 0; i < 2; ++i) {
      int lin = tid + i * 256;
      int r = lin >> 2, c4 = (lin & 3) * 4;
      int row = row0 + r;
      float4 v = {0.0f, 0.0f, 0.0f, 0.0f};
      if (row < M) {
        if (a_mode == 1) {
          int b_ = row >> band_log2;
          int t_ = band_lo + (row & bmask);
          v = *(const float4*)(A + (size_t)((b_ << 8) + t_) * 256 + kt + c4);
        } else {  // a_mode 2
          int b_ = row >> band_log2;
          int p_ = band_lo + (row & bmask);
          const float* p0 = A + (size_t)((b_ << 8) + 2 * p_) * 256 + kt + c4;
          float4 x0 = {0.0f, 0.0f, 0.0f, 0.0f};
          if (2 * p_ != 0) x0 = *(const float4*)p0;
          float4 x1 = *(const float4*)(p0 + 256);
          v.x = x0.x + x1.x; v.y = x0.y + x1.y;
          v.z = x0.z + x1.z; v.w = x0.w + x1.w;
        }
      }
      As[c4 + 0][r] = v.x; As[c4 + 1][r] = v.y;
      As[c4 + 2][r] = v.z; As[c4 + 3][r] = v.w;
    }
#pragma unroll
    for (int i = 0; i < 2; ++i) {
      int lin = tid + i * 256;
      int kr = lin >> 5, c4 = (lin & 31) * 4;
      float4 v = *(const float4*)(Bm + (size_t)(kt + kr) * N + col0 + c4);
      *(float4*)&Bs[kr][c4] = v;
    }
    __syncthreads();
#pragma unroll
    for (int kk = 0; kk < 16; ++kk) {
      float a[8], bb[8];
      *(float4*)&a[0] = *(const float4*)&As[kk][ty * 8];
      *(float4*)&a[4] = *(const float4*)&As[kk][ty * 8 + 4];
      *(float4*)&bb[0] = *(const float4*)&Bs[kk][tx * 8];
      *(float4*)&bb[4] = *(const float4*)&Bs[kk][tx * 8 + 4];
#pragma unroll
      for (int i = 0; i < 8; ++i)
#pragma unroll
        for (int j = 0; j < 8; ++j) acc[i][j] += a[i] * bb[j];
    }
    __syncthreads();
  }

#pragma unroll
  for (int i = 0; i < 8; ++i) {
    int row = row0 + ty * 8 + i;
    if (row >= M) continue;
    int b_ = 0, t_ = 0, par = 0;
    float m = 1.0f;
    if (epi_mode == 2) {
      b_ = row >> band_log2;
      t_ = band_lo + (row & bmask);
      par = dep_heads[(b_ << 8) + t_];
      m = (par != t_) ? 1.0f : 0.0f;
    }
    float vv[8];
#pragma unroll
    for (int j = 0; j < 8; ++j) {
      int col = col0 + tx * 8 + j;
      float v = acc[i][j];
      if (bias) v += bias[col];
      if (epi_mode == 2) {
        float xwv = xWf[(size_t)((b_ << 8) + par) * 256 + col];
        float cv = c_buf[(size_t)((b_ << 8) + t_) * 256 + col];
        v = sigm(v + xwv) * cv * m;
      }
      vv[j] = v;
    }
    float* cp = (float*)Cv + (size_t)row * N + col0 + tx * 8;
    *(float4*)cp = *(float4*)&vv[0];
    *(float4*)(cp + 4) = *(float4*)&vv[4];
  }
}

// ---------------- tree leaves: t in [128,256) ----------------
__global__ __launch_bounds__(256) void k_leaves(
    const float* __restrict__ xWiou, float* __restrict__ h_buf,
    float* __restrict__ c_buf) {
  int r = blockIdx.x;  // 0..8191
  int b = r >> 7, t = 128 + (r & 127);
  size_t row = (size_t)((b << 8) + t);
  int j = threadIdx.x;
  float i = xWiou[row * 768 + j];
  float o = xWiou[row * 768 + 256 + j];
  float u = xWiou[row * 768 + 512 + j];
  float c = sigm(i) * tanhf(u);
  float h = sigm(o) * tanhf(c);
  c_buf[row * 256 + j] = c;
  h_buf[row * 256 + j] = h;
}

// ---------------- tree stage update ----------------
__global__ __launch_bounds__(256) void k_update(
    const float* __restrict__ xWiou, const float* __restrict__ iou_lin,
    const float* __restrict__ FC, float* __restrict__ h_buf,
    float* __restrict__ c_buf, int plo, int nplog2) {
  int r = blockIdx.x, j = threadIdx.x;
  int npm = (1 << nplog2) - 1;
  int b = r >> nplog2, loc = r & npm, p = plo + loc;
  size_t row = (size_t)((b << 8) + p);
  float i = xWiou[row * 768 + j] + iou_lin[(size_t)r * 768 + j];
  float o = xWiou[row * 768 + 256 + j] + iou_lin[(size_t)r * 768 + 256 + j];
  float u = xWiou[row * 768 + 512 + j] + iou_lin[(size_t)r * 768 + 512 + j];
  int nch = 2 << nplog2;
  float fc = FC[(size_t)(b * nch + 2 * loc) * 256 + j] +
             FC[(size_t)(b * nch + 2 * loc + 1) * 256 + j];
  float c = sigm(i) * tanhf(u) + fc;
  float h = sigm(o) * tanhf(c);
  c_buf[row * 256 + j] = c;
  h_buf[row * 256 + j] = h;
}

// ---------------- classifier ----------------
__global__ __launch_bounds__(256) void k_classifier(
    const float* __restrict__ h_buf, const int* __restrict__ root_idx,
    const float* __restrict__ W1, const float* __restrict__ b1,
    const float* __restrict__ W2, const float* __restrict__ b2,
    float* __restrict__ out) {
  int b = blockIdx.x, j = threadIdx.x;
  __shared__ float hroot[256];
  __shared__ float hid[256];
  int root = root_idx[b];
  hroot[j] = h_buf[(size_t)((b << 8) + root) * 256 + j];
  __syncthreads();
  float acc = b1[j];
  for (int k = 0; k < 256; ++k) acc += hroot[k] * W1[k * 256 + j];
  hid[j] = fmaxf(acc, 0.0f);
  __syncthreads();
  if (j < 10) {
    float o = b2[j];
    for (int k = 0; k < 256; ++k) o += hid[k] * W2[k * 10 + j];
    out[b * 10 + j] = o;
  }
}

// ---------------------------------------------------------------------------
extern "C" void kernel_launch(void* const* d_in, const int* in_sizes, int n_in,
                              void* d_out, int out_size, void* d_ws,
                              size_t ws_size, hipStream_t stream) {
  (void)in_sizes; (void)n_in; (void)out_size; (void)ws_size;
  const float* tf       = (const float*)d_in[0];
  const int*   pos_ids  = (const int*)d_in[1];
  const int*   dep_ids  = (const int*)d_in[2];
  const int*   e1       = (const int*)d_in[3];
  const int*   e2       = (const int*)d_in[4];
  const int*   sdp      = (const int*)d_in[5];
  const int*   heads    = (const int*)d_in[6];
  const int*   root     = (const int*)d_in[7];
  const float* pos_tab  = (const float*)d_in[8];
  const float* dep_tab  = (const float*)d_in[9];
  const float* dist_tab = (const float*)d_in[10];
  const float* sdp_tab  = (const float*)d_in[11];
  const float* W_ft     = (const float*)d_in[12];
  const float* b_ft     = (const float*)d_in[13];
  const float* Wih_f    = (const float*)d_in[14];
  const float* Whh_f    = (const float*)d_in[15];
  const float* bl_f     = (const float*)d_in[16];
  const float* Wih_b    = (const float*)d_in[17];
  const float* Whh_b    = (const float*)d_in[18];
  const float* bl_b     = (const float*)d_in[19];
  const float* W_iou    = (const float*)d_in[20];
  const float* U_iou    = (const float*)d_in[21];
  const float* b_iou    = (const float*)d_in[22];
  const float* Wf_t     = (const float*)d_in[23];
  const float* Uf_t     = (const float*)d_in[24];
  const float* bf_t     = (const float*)d_in[25];
  const float* W1       = (const float*)d_in[26];
  const float* b1       = (const float*)d_in[27];
  const float* W2       = (const float*)d_in[28];
  const float* b2       = (const float*)d_in[29];

  // ---- workspace (lifetime-overlaid; peak < proven-safe 122.7 MB)
  char* ws = (char*)d_ws;
  __half* XF    = (__half*)(ws + 0ull);            // 33.5MB  phase2->3 (staged layout)
  __half* XB    = (__half*)(ws + 33554432ull);     // 33.5MB  phase2->3 (staged layout)
  float*  XWIOU = (float*)(ws + 0ull);             // 50.3MB  phase5->6
  float*  XWF   = (float*)(ws + 50331648ull);      // 16.8MB  phase5->6
  __half* XT    = (__half*)(ws + 67108864ull);     // 17.8MB  phase3->5
  float*  FCb   = (float*)(ws + 67108864ull);      //  8.4MB  phase6
  float*  IOUL  = (float*)(ws + 75497472ull);      // 12.6MB  phase6
  float*  H     = (float*)(ws + 88080384ull);      // 16.8MB  phase6
  __half* T     = (__half*)(ws + 88080384ull);     // 16.8MB  phase1->2 (over H)
  __half* HexS  = (__half*)(ws + 88080384ull);     // 16.8MB  phase3 (over T/H)
  float*  C     = (float*)(ws + 104857600ull);     // 16.8MB  phase6
  // packs live inside C region (dead before C written):
  __half* BTft  = (__half*)(ws + 104857600ull);    // 950,272
  __half* BTwhf = (__half*)(ws + 105807872ull);    // 1,048,576
  __half* BTwhb = (__half*)(ws + 106856448ull);    // 1,048,576
  __half* BTiou = (__half*)(ws + 107905024ull);    // 835,584
  __half* BTf   = (__half*)(ws + 108740608ull);    // 278,528
  __half* WBf   = (__half*)(ws + 109019136ull);    // 524,288
  __half* WBb   = (__half*)(ws + 109543424ull);    // 524,288
  unsigned int* FLG = (unsigned int*)(ws + 110198784ull);  // 16,384

  EmbArgs ea{tf, pos_ids, dep_ids, e1, e2, sdp, pos_tab, dep_tab, dist_tab, sdp_tab};

  // 0. weight packs + flag zero
  k_packB<<<dim3(912, 2), dim3(256), 0, stream>>>(W_ft, BTft, 512, 928);
  k_zft<<<dim3(32), dim3(256), 0, stream>>>(BTft);
  k_packB<<<dim3(512, 4), dim3(256), 0, stream>>>(Wih_f, BTwhf, 1024, 512);
  k_packB<<<dim3(512, 4), dim3(256), 0, stream>>>(Wih_b, BTwhb, 1024, 512);
  k_packB<<<dim3(544, 3), dim3(256), 0, stream>>>(W_iou, BTiou, 768, 544);
  k_packB<<<dim3(544, 1), dim3(256), 0, stream>>>(Wf_t, BTf, 256, 544);
  k_packWB<<<dim3(1024), dim3(256), 0, stream>>>(Whh_f, WBf);
  k_packWB<<<dim3(1024), dim3(256), 0, stream>>>(Whh_b, WBb);
  k_zero<<<dim3(8), dim3(256), 0, stream>>>(FLG, 2048);

  // 1. T = tanh(embed @ W_ft + b_ft)  [f16 out, embed fused]
  k_mgemm<<<dim3(4, 128), dim3(256), 0, stream>>>(
      nullptr, BTft, b_ft, (void*)T, 512, 928, 0, 1, 1, 1, ea);
  // 2. xW_f / xW_b  [f16 out, LSTM staging layout]
  k_mgemm<<<dim3(8, 128), dim3(256), 0, stream>>>(
      T, BTwhf, bl_f, (void*)XF, 1024, 512, 512, 0, 0, 2, ea);
  k_mgemm<<<dim3(8, 128), dim3(256), 0, stream>>>(
      T, BTwhb, bl_b, (void*)XB, 1024, 512, 512, 0, 0, 2, ea);
  // 3. BiLSTM -> XT cols [0,512)   (HexS overlays dead T)
  k_lstm3<<<dim3(8), dim3(256), 0, stream>>>(XF, XB, WBf, WBb, HexS, FLG, XT);
  // 4. dep_emb -> XT cols [512,544)
  k_depfill<<<dim3(2048), dim3(256), 0, stream>>>(dep_ids, dep_tab, XT);
  // 5. xWiou / xWf  [f32 out]
  k_mgemm<<<dim3(6, 128), dim3(256), 0, stream>>>(
      XT, BTiou, b_iou, (void*)XWIOU, 768, 544, 544, 0, 0, 0, ea);
  k_mgemm<<<dim3(2, 128), dim3(256), 0, stream>>>(
      XT, BTf, bf_t, (void*)XWF, 256, 544, 544, 0, 0, 0, ea);
  // 6. tree: leaves then levels bottom-up (exact vs 9 dense sweeps)
  k_leaves<<<dim3(8192), dim3(256), 0, stream>>>(XWIOU, H, C);
  const int plos[8] = {64, 32, 16, 8, 4, 2, 1, 0};
  const int lgs[8]  = {6, 5, 4, 3, 2, 1, 0, 0};
  for (int s = 0; s < 8; ++s) {
    int plo = plos[s], lg = lgs[s];
    int npar = 1 << lg;
    int Mch = 64 * 2 * npar;
    int Mp = 64 * npar;
    k_gemm<<<dim3(2, (Mch + 127) / 128), dim3(256), 0, stream>>>(
        H, Uf_t, nullptr, (void*)FCb, Mch, 256, 256, 0,
        1, 2 * plo, lg + 1, 2, heads, XWF, C);
    k_gemm<<<dim3(6, (Mp + 127) / 128), dim3(256), 0, stream>>>(
        H, U_iou, nullptr, (void*)IOUL, Mp, 768, 256, 0,
        2, plo, lg, 0, nullptr, nullptr, nullptr);
    k_update<<<dim3(Mp), dim3(256), 0, stream>>>(XWIOU, IOUL, FCb, H, C, plo, lg);
  }
  // 7. classifier
  k_classifier<<<dim3(64), dim3(256), 0, stream>>>(H, root, W1, b1, W2, b2,
                                                   (float*)d_out);
}

// Round 9
// 2838.634 us; speedup vs baseline: 1.3379x; 1.3379x over previous
//
#include <hip/hip_runtime.h>
#include <hip/hip_fp16.h>
#include <math.h>

// ---------------------------------------------------------------------------
// RelationExtractionModel B=64,T=256. Round 9: revert BiLSTM to 16-block
// geometry (32-unit slices, bfrag[2][8]=64 VGPR, no spill) + merge round-8
// wins: coalesced xW staging [t][slice8][gate4][b][u32] and ownership remap
// (b=tid>>2) for register-direct contiguous publish + simplified gather.
// ---------------------------------------------------------------------------

typedef _Float16 f16x8 __attribute__((ext_vector_type(8)));
typedef float    f32x4 __attribute__((ext_vector_type(4)));

union PK { _Float16 h[8]; unsigned long long u64[2]; f16x8 v; };

__device__ __forceinline__ float sigm(float x) { return 1.0f / (1.0f + expf(-x)); }

struct EmbArgs {
  const float* tf; const int* pos_ids; const int* dep_ids;
  const int* e1; const int* e2; const int* sdp;
  const float* pos_tab; const float* dep_tab; const float* dist_tab;
  const float* sdp_tab;
};

// ---------------- weight pack: BT[n*Kpad+k] = f16(W[k*N+n]) ----------------
__global__ __launch_bounds__(256) void k_packB(const float* __restrict__ W,
                                               __half* __restrict__ BT,
                                               int N, int Kpad) {
  int k = blockIdx.x;
  int n = blockIdx.y * 256 + threadIdx.x;
  BT[(size_t)n * Kpad + k] = __float2half_rn(W[(size_t)k * N + n]);
}
__global__ __launch_bounds__(256) void k_zft(__half* __restrict__ BT) {
  int i = blockIdx.x * 256 + threadIdx.x;  // 512 rows x 16 pad cols
  int n = i >> 4, kk = i & 15;
  BT[(size_t)n * 928 + 912 + kk] = __float2half_rn(0.0f);
}

// ---- LSTM weight pack (8 slices of 32 units):
// WB[((j*128 + c)*256) + k] = f16(Whh[k][ (c&3)*256 + j*32 + (c>>2) ])
__global__ __launch_bounds__(256) void k_packWB(const float* __restrict__ W,
                                                __half* __restrict__ WB) {
  int i = blockIdx.x * 256 + threadIdx.x;  // 0..262143
  int k = i & 255;
  int c = (i >> 8) & 127;
  int j = i >> 15;
  int col = (c & 3) * 256 + j * 32 + (c >> 2);
  WB[i] = __float2half_rn(W[(size_t)k * 1024 + col]);
}

// ---------------- zero the sync flags ----------------
__global__ __launch_bounds__(256) void k_zero(unsigned int* __restrict__ p,
                                              int n) {
  int i = blockIdx.x * 256 + threadIdx.x;
  if (i < n) p[i] = 0u;
}

// ---------------- MFMA f16 GEMM ----------------
// out_mode: 0 = f32 row-major, 1 = f16 row-major, 2 = f16 LSTM staging layout
// [t][slice8][gate4][b64][u32] (M must be 16384 rows = b*256+t, N=1024).
__global__ __launch_bounds__(256) void k_mgemm(
    const __half* __restrict__ A16, const __half* __restrict__ BT,
    const float* __restrict__ bias, void* __restrict__ out,
    int N, int K, int lda, int a_embed, int act_tanh, int out_mode,
    EmbArgs ea) {
  __shared__ _Float16 As[128 * 40];
  __shared__ _Float16 Bs[128 * 40];
  int tid = threadIdx.x;
  int lane = tid & 63, wave = tid >> 6;
  int wm = wave & 1, wn = wave >> 1;
  int col0 = blockIdx.x * 128, row0 = blockIdx.y * 128;

  f32x4 acc[4][4];
#pragma unroll
  for (int i = 0; i < 4; ++i)
#pragma unroll
    for (int j = 0; j < 4; ++j) acc[i][j] = (f32x4)0.0f;

  for (int kt = 0; kt < K; kt += 32) {
    __syncthreads();
#pragma unroll
    for (int it = 0; it < 2; ++it) {
      int lin = tid + it * 256;
      int r = lin & 127, kh8 = (lin >> 7) * 8;
      f16x8 va;
      if (!a_embed) {
        va = *(const f16x8*)(A16 + (size_t)(row0 + r) * lda + kt + kh8);
      } else {
        int row = row0 + r;
        int k0 = kt + kh8;
        if (k0 >= 912) {
          va = (f16x8)(_Float16)0.0f;
        } else {
          const float* src;
          if (k0 < 768) {
            src = ea.tf + (size_t)row * 768 + k0;
          } else {
            int b_ = row >> 8, t_ = row & 255;
            if (k0 < 800) src = ea.pos_tab + ea.pos_ids[row] * 32 + (k0 - 768);
            else if (k0 < 832) src = ea.dep_tab + ea.dep_ids[row] * 32 + (k0 - 800);
            else if (k0 < 864) {
              int d = t_ - ea.e1[b_] + 10; d = d < 0 ? 0 : (d > 20 ? 20 : d);
              src = ea.dist_tab + d * 32 + (k0 - 832);
            } else if (k0 < 896) {
              int d = t_ - ea.e2[b_] + 10; d = d < 0 ? 0 : (d > 20 ? 20 : d);
              src = ea.dist_tab + d * 32 + (k0 - 864);
            } else {
              src = ea.sdp_tab + ea.sdp[row] * 16 + (k0 - 896);
            }
          }
          float4 a = *(const float4*)src;
          float4 b2 = *(const float4*)(src + 4);
          va[0] = (_Float16)a.x;  va[1] = (_Float16)a.y;
          va[2] = (_Float16)a.z;  va[3] = (_Float16)a.w;
          va[4] = (_Float16)b2.x; va[5] = (_Float16)b2.y;
          va[6] = (_Float16)b2.z; va[7] = (_Float16)b2.w;
        }
      }
      *(f16x8*)&As[r * 40 + kh8] = va;
      f16x8 vb = *(const f16x8*)(BT + (size_t)(col0 + r) * K + kt + kh8);
      *(f16x8*)&Bs[r * 40 + kh8] = vb;
    }
    __syncthreads();
    f16x8 af[4], bf[4];
    int kq = (lane >> 4) * 8;
#pragma unroll
    for (int mt = 0; mt < 4; ++mt)
      af[mt] = *(const f16x8*)&As[(wm * 64 + mt * 16 + (lane & 15)) * 40 + kq];
#pragma unroll
    for (int nt = 0; nt < 4; ++nt)
      bf[nt] = *(const f16x8*)&Bs[(wn * 64 + nt * 16 + (lane & 15)) * 40 + kq];
#pragma unroll
    for (int mt = 0; mt < 4; ++mt)
#pragma unroll
      for (int nt = 0; nt < 4; ++nt)
        acc[mt][nt] = __builtin_amdgcn_mfma_f32_16x16x32_f16(
            af[mt], bf[nt], acc[mt][nt], 0, 0, 0);
  }

#pragma unroll
  for (int mt = 0; mt < 4; ++mt) {
#pragma unroll
    for (int nt = 0; nt < 4; ++nt) {
      int col = col0 + wn * 64 + nt * 16 + (lane & 15);
      float bv = bias[col];
#pragma unroll
      for (int r = 0; r < 4; ++r) {
        int row = row0 + wm * 64 + mt * 16 + (lane >> 4) * 4 + r;
        float v = acc[mt][nt][r] + bv;
        if (act_tanh) v = tanhf(v);
        if (out_mode == 0) {
          ((float*)out)[(size_t)row * N + col] = v;
        } else if (out_mode == 1) {
          ((__half*)out)[(size_t)row * N + col] = __float2half_rn(v);
        } else {
          // LSTM staging: [t][slice8][gate4][b][32 units]
          int b_ = row >> 8, t_ = row & 255;
          int g_ = col >> 8, u_ = col & 255;
          int sl = u_ >> 5, ul = u_ & 31;
          ((__half*)out)[((((size_t)(t_ * 8 + sl) * 4 + g_) * 64 + b_) * 32) + ul] =
              __float2half_rn(v);
        }
      }
    }
  }
}

// ---------------- BiLSTM v5: 16 blocks = 2 dirs x 8 unit-slices -----------
// 32 units/slice in VGPR B-fragments (64 VGPRs, no spill). Thread tid owns
// batch tid>>2, units (tid&3)*8. Register-direct contiguous publish, 7-peer
// store-flags, contiguous normal-load gather, coalesced xW staging reads.
__global__ __launch_bounds__(256, 1) void k_lstm3(
    const __half* __restrict__ XFs, const __half* __restrict__ XBs,
    const __half* __restrict__ WBf, const __half* __restrict__ WBb,
    __half* __restrict__ HexS, unsigned int* __restrict__ flags,
    __half* __restrict__ XT) {
  int bx = blockIdx.x;          // 0..15
  int dir = bx >> 3, slice = bx & 7;
  int tid = threadIdx.x;
  int lane = tid & 63, wave = tid >> 6;
  const __half* xWs = dir ? XBs : XFs;
  const __half* WB = dir ? WBb : WBf;
  __half* hexd = HexS + (size_t)dir * 256 * 16384;  // [step][slice8][b64][u32]
  unsigned int* flg = flags + dir * 2048;           // [slice][step]

  __shared__ _Float16 H[64 * 266];   // [b][u], row stride 266 f16
  __shared__ float GT[64 * 133];     // [b][c], row stride 133 dw (c=ul*4+g)

  // ---- preload B-fragments (resident all 256 steps): 128 cols x 256 k
  f16x8 bfrag[2][8];
#pragma unroll
  for (int nt2 = 0; nt2 < 2; ++nt2) {
    int c = (wave * 2 + nt2) * 16 + (lane & 15);
#pragma unroll
    for (int kt = 0; kt < 8; ++kt)
      bfrag[nt2][kt] = *(const f16x8*)(
          WB + ((size_t)(slice * 128 + c) * 256) + kt * 32 + (lane >> 4) * 8);
  }
  // ---- zero H
  for (int i = tid; i < 64 * 266 / 8; i += 256)
    ((f16x8*)H)[i] = (f16x8)(_Float16)0.0f;
  float cst[8];
#pragma unroll
  for (int p = 0; p < 8; ++p) cst[p] = 0.0f;
  int b_own = tid >> 2;
  int uc = tid & 3;   // 8-unit chunk within the 32-unit slice
  __syncthreads();

  for (int s = 0; s < 256; ++s) {
    int t = dir ? (255 - s) : s;
    // prefetch xW gates, fully coalesced (4KB contiguous per gate instr)
    const __half* xwp = xWs + ((size_t)(t * 8 + slice) * 8192) + tid * 8;
    f16x8 xwg[4];
#pragma unroll
    for (int g = 0; g < 4; ++g) xwg[g] = *(const f16x8*)(xwp + g * 2048);

    // ---- MFMA: gates[64 b, 128 c] = H[64,256] @ Wslice[256,128]
    f32x4 acc[4][2];
#pragma unroll
    for (int mt = 0; mt < 4; ++mt)
#pragma unroll
      for (int nt2 = 0; nt2 < 2; ++nt2) acc[mt][nt2] = (f32x4)0.0f;
#pragma unroll
    for (int kt = 0; kt < 8; ++kt) {
      f16x8 a[4];
#pragma unroll
      for (int mt = 0; mt < 4; ++mt)
        a[mt] = *(const f16x8*)&H[(mt * 16 + (lane & 15)) * 266 + kt * 32 +
                                  (lane >> 4) * 8];
#pragma unroll
      for (int mt = 0; mt < 4; ++mt)
#pragma unroll
        for (int nt2 = 0; nt2 < 2; ++nt2)
          acc[mt][nt2] = __builtin_amdgcn_mfma_f32_16x16x32_f16(
              a[mt], bfrag[nt2][kt], acc[mt][nt2], 0, 0, 0);
    }
    __syncthreads();  // H consumed; GT fully read (prev update)
    // ---- transpose C-layout -> GT[b][c]
#pragma unroll
    for (int mt = 0; mt < 4; ++mt)
#pragma unroll
      for (int nt2 = 0; nt2 < 2; ++nt2) {
        int col = (wave * 2 + nt2) * 16 + (lane & 15);
#pragma unroll
        for (int r = 0; r < 4; ++r) {
          int b = mt * 16 + (lane >> 4) * 4 + r;
          GT[b * 133 + col] = acc[mt][nt2][r];
        }
      }
    __syncthreads();
    // ---- c/h update for own (b_own, units uc*8..uc*8+7)
    PK hv;
#pragma unroll
    for (int p = 0; p < 8; ++p) {
      int ul = uc * 8 + p;
      float4 g4 = *(const float4*)&GT[b_own * 133 + 4 * ul];
      float gi = g4.x + (float)xwg[0][p];
      float gf = g4.y + (float)xwg[1][p];
      float gg = g4.z + (float)xwg[2][p];
      float go = g4.w + (float)xwg[3][p];
      cst[p] = sigm(gf) * cst[p] + sigm(gi) * tanhf(gg);
      float hn = sigm(go) * tanhf(cst[p]);
      hv.h[p] = (_Float16)hn;
    }
    // own h -> LDS H
    *(f16x8*)&H[b_own * 266 + slice * 32 + uc * 8] = hv.v;

    if (s < 255) {
      __half* hexq = hexd + (size_t)s * 16384;
      // ---- publish directly from registers (block-contiguous 4KB)
      unsigned long long* dst =
          (unsigned long long*)(hexq + slice * 2048 + tid * 8);
      __hip_atomic_store(&dst[0], hv.u64[0], __ATOMIC_RELAXED,
                         __HIP_MEMORY_SCOPE_AGENT);
      __hip_atomic_store(&dst[1], hv.u64[1], __ATOMIC_RELAXED,
                         __HIP_MEMORY_SCOPE_AGENT);
      // drain own wave's publish stores to the LLC, then block rendezvous
      asm volatile("s_waitcnt vmcnt(0)" ::: "memory");
      __syncthreads();
      if (tid == 0)
        __hip_atomic_store(&flg[(slice << 8) + s], 1u, __ATOMIC_RELAXED,
                           __HIP_MEMORY_SCOPE_AGENT);
      // XT store AFTER flag (out of the drain path)
      *(f16x8*)(XT + (size_t)((b_own << 8) + t) * 544 + dir * 256 +
                slice * 32 + uc * 8) = hv.v;
      // poll the 7 peer flags in parallel (lanes 0..7)
      if (tid < 8 && tid != slice) {
        while (__hip_atomic_load(&flg[(tid << 8) + s], __ATOMIC_RELAXED,
                                 __HIP_MEMORY_SCOPE_AGENT) == 0u)
          __builtin_amdgcn_s_sleep(1);
      }
      __syncthreads();
      // ---- gather 7 peer slices, contiguous normal loads (step-unique)
#pragma unroll
      for (int i = 0; i < 7; ++i) {
        int ps = i + (i >= slice ? 1 : 0);
        f16x8 pv = *(const f16x8*)(hexq + ps * 2048 + tid * 8);
        *(f16x8*)&H[b_own * 266 + ps * 32 + uc * 8] = pv;
      }
      __syncthreads();  // H complete before next step's MFMA
    } else {
      *(f16x8*)(XT + (size_t)((b_own << 8) + t) * 544 + dir * 256 +
                slice * 32 + uc * 8) = hv.v;
    }
  }
}

// ---------------- fill dep_emb into x_tree cols [512,544), f16 -------------
__global__ __launch_bounds__(256) void k_depfill(
    const int* __restrict__ dep_ids, const float* __restrict__ dep_tab,
    __half* __restrict__ XT) {
  int e = blockIdx.x * 256 + threadIdx.x;  // 0..524287
  int row = e >> 5, k = e & 31;
  XT[(size_t)row * 544 + 512 + k] = __float2half_rn(dep_tab[dep_ids[row] * 32 + k]);
}

// ---------------- fp32 VALU GEMM (tree stages only) ----------------
__global__ __launch_bounds__(256) void k_gemm(
    const float* __restrict__ A, const float* __restrict__ Bm,
    const float* __restrict__ bias, void* __restrict__ Cv,
    int M, int N, int K, int lda,
    int a_mode, int band_lo, int band_log2,
    int epi_mode,
    const int* __restrict__ dep_heads,
    const float* __restrict__ xWf, const float* __restrict__ c_buf) {
  __shared__ float As[16][132];
  __shared__ float Bs[16][132];
  int tid = threadIdx.x;
  int col0 = blockIdx.x * 128;
  int row0 = blockIdx.y * 128;
  int tx = tid & 15, ty = tid >> 4;
  float acc[8][8];
#pragma unroll
  for (int i = 0; i < 8; ++i)
#pragma unroll
    for (int j = 0; j < 8; ++j) acc[i][j] = 0.0f;

  int bmask = (1 << band_log2) - 1;
  for (int kt = 0; kt < K; kt += 16) {
#pragma unroll
    for (int i = 0; i < 2; ++i) {
      int lin = tid + i * 256;
      int r = lin >> 2, c4 = (lin & 3) * 4;
      int row = row0 + r;
      float4 v = {0.0f, 0.0f, 0.0f, 0.0f};
      if (row < M) {
        if (a_mode == 1) {
          int b_ = row >> band_log2;
          int t_ = band_lo + (row & bmask);
          v = *(const float4*)(A + (size_t)((b_ << 8) + t_) * 256 + kt + c4);
        } else {  // a_mode 2
          int b_ = row >> band_log2;
          int p_ = band_lo + (row & bmask);
          const float* p0 = A + (size_t)((b_ << 8) + 2 * p_) * 256 + kt + c4;
          float4 x0 = {0.0f, 0.0f, 0.0f, 0.0f};
          if (2 * p_ != 0) x0 = *(const float4*)p0;
          float4 x1 = *(const float4*)(p0 + 256);
          v.x = x0.x + x1.x; v.y = x0.y + x1.y;
          v.z = x0.z + x1.z; v.w = x0.w + x1.w;
        }
      }
      As[c4 + 0][r] = v.x; As[c4 + 1][r] = v.y;
      As[c4 + 2][r] = v.z; As[c4 + 3][r] = v.w;
    }
#pragma unroll
    for (int i = 0; i < 2; ++i) {
      int lin = tid + i * 256;
      int kr = lin >> 5, c4 = (lin & 31) * 4;
      float4 v = *(const float4*)(Bm + (size_t)(kt + kr) * N + col0 + c4);
      *(float4*)&Bs[kr][c4] = v;
    }
    __syncthreads();
#pragma unroll
    for (int kk = 0; kk < 16; ++kk) {
      float a[8], bb[8];
      *(float4*)&a[0] = *(const float4*)&As[kk][ty * 8];
      *(float4*)&a[4] = *(const float4*)&As[kk][ty * 8 + 4];
      *(float4*)&bb[0] = *(const float4*)&Bs[kk][tx * 8];
      *(float4*)&bb[4] = *(const float4*)&Bs[kk][tx * 8 + 4];
#pragma unroll
      for (int i = 0; i < 8; ++i)
#pragma unroll
        for (int j = 0; j < 8; ++j) acc[i][j] += a[i] * bb[j];
    }
    __syncthreads();
  }

#pragma unroll
  for (int i = 0; i < 8; ++i) {
    int row = row0 + ty * 8 + i;
    if (row >= M) continue;
    int b_ = 0, t_ = 0, par = 0;
    float m = 1.0f;
    if (epi_mode == 2) {
      b_ = row >> band_log2;
      t_ = band_lo + (row & bmask);
      par = dep_heads[(b_ << 8) + t_];
      m = (par != t_) ? 1.0f : 0.0f;
    }
    float vv[8];
#pragma unroll
    for (int j = 0; j < 8; ++j) {
      int col = col0 + tx * 8 + j;
      float v = acc[i][j];
      if (bias) v += bias[col];
      if (epi_mode == 2) {
        float xwv = xWf[(size_t)((b_ << 8) + par) * 256 + col];
        float cv = c_buf[(size_t)((b_ << 8) + t_) * 256 + col];
        v = sigm(v + xwv) * cv * m;
      }
      vv[j] = v;
    }
    float* cp = (float*)Cv + (size_t)row * N + col0 + tx * 8;
    *(float4*)cp = *(float4*)&vv[0];
    *(float4*)(cp + 4) = *(float4*)&vv[4];
  }
}

// ---------------- tree leaves: t in [128,256) ----------------
__global__ __launch_bounds__(256) void k_leaves(
    const float* __restrict__ xWiou, float* __restrict__ h_buf,
    float* __restrict__ c_buf) {
  int r = blockIdx.x;  // 0..8191
  int b = r >> 7, t = 128 + (r & 127);
  size_t row = (size_t)((b << 8) + t);
  int j = threadIdx.x;
  float i = xWiou[row * 768 + j];
  float o = xWiou[row * 768 + 256 + j];
  float u = xWiou[row * 768 + 512 + j];
  float c = sigm(i) * tanhf(u);
  float h = sigm(o) * tanhf(c);
  c_buf[row * 256 + j] = c;
  h_buf[row * 256 + j] = h;
}

// ---------------- tree stage update ----------------
__global__ __launch_bounds__(256) void k_update(
    const float* __restrict__ xWiou, const float* __restrict__ iou_lin,
    const float* __restrict__ FC, float* __restrict__ h_buf,
    float* __restrict__ c_buf, int plo, int nplog2) {
  int r = blockIdx.x, j = threadIdx.x;
  int npm = (1 << nplog2) - 1;
  int b = r >> nplog2, loc = r & npm, p = plo + loc;
  size_t row = (size_t)((b << 8) + p);
  float i = xWiou[row * 768 + j] + iou_lin[(size_t)r * 768 + j];
  float o = xWiou[row * 768 + 256 + j] + iou_lin[(size_t)r * 768 + 256 + j];
  float u = xWiou[row * 768 + 512 + j] + iou_lin[(size_t)r * 768 + 512 + j];
  int nch = 2 << nplog2;
  float fc = FC[(size_t)(b * nch + 2 * loc) * 256 + j] +
             FC[(size_t)(b * nch + 2 * loc + 1) * 256 + j];
  float c = sigm(i) * tanhf(u) + fc;
  float h = sigm(o) * tanhf(c);
  c_buf[row * 256 + j] = c;
  h_buf[row * 256 + j] = h;
}

// ---------------- classifier ----------------
__global__ __launch_bounds__(256) void k_classifier(
    const float* __restrict__ h_buf, const int* __restrict__ root_idx,
    const float* __restrict__ W1, const float* __restrict__ b1,
    const float* __restrict__ W2, const float* __restrict__ b2,
    float* __restrict__ out) {
  int b = blockIdx.x, j = threadIdx.x;
  __shared__ float hroot[256];
  __shared__ float hid[256];
  int root = root_idx[b];
  hroot[j] = h_buf[(size_t)((b << 8) + root) * 256 + j];
  __syncthreads();
  float acc = b1[j];
  for (int k = 0; k < 256; ++k) acc += hroot[k] * W1[k * 256 + j];
  hid[j] = fmaxf(acc, 0.0f);
  __syncthreads();
  if (j < 10) {
    float o = b2[j];
    for (int k = 0; k < 256; ++k) o += hid[k] * W2[k * 10 + j];
    out[b * 10 + j] = o;
  }
}

// ---------------------------------------------------------------------------
extern "C" void kernel_launch(void* const* d_in, const int* in_sizes, int n_in,
                              void* d_out, int out_size, void* d_ws,
                              size_t ws_size, hipStream_t stream) {
  (void)in_sizes; (void)n_in; (void)out_size; (void)ws_size;
  const float* tf       = (const float*)d_in[0];
  const int*   pos_ids  = (const int*)d_in[1];
  const int*   dep_ids  = (const int*)d_in[2];
  const int*   e1       = (const int*)d_in[3];
  const int*   e2       = (const int*)d_in[4];
  const int*   sdp      = (const int*)d_in[5];
  const int*   heads    = (const int*)d_in[6];
  const int*   root     = (const int*)d_in[7];
  const float* pos_tab  = (const float*)d_in[8];
  const float* dep_tab  = (const float*)d_in[9];
  const float* dist_tab = (const float*)d_in[10];
  const float* sdp_tab  = (const float*)d_in[11];
  const float* W_ft     = (const float*)d_in[12];
  const float* b_ft     = (const float*)d_in[13];
  const float* Wih_f    = (const float*)d_in[14];
  const float* Whh_f    = (const float*)d_in[15];
  const float* bl_f     = (const float*)d_in[16];
  const float* Wih_b    = (const float*)d_in[17];
  const float* Whh_b    = (const float*)d_in[18];
  const float* bl_b     = (const float*)d_in[19];
  const float* W_iou    = (const float*)d_in[20];
  const float* U_iou    = (const float*)d_in[21];
  const float* b_iou    = (const float*)d_in[22];
  const float* Wf_t     = (const float*)d_in[23];
  const float* Uf_t     = (const float*)d_in[24];
  const float* bf_t     = (const float*)d_in[25];
  const float* W1       = (const float*)d_in[26];
  const float* b1       = (const float*)d_in[27];
  const float* W2       = (const float*)d_in[28];
  const float* b2       = (const float*)d_in[29];

  // ---- workspace (lifetime-overlaid; peak < proven-safe 122.7 MB)
  char* ws = (char*)d_ws;
  __half* XF    = (__half*)(ws + 0ull);            // 33.5MB  phase2->3 (staged layout)
  __half* XB    = (__half*)(ws + 33554432ull);     // 33.5MB  phase2->3 (staged layout)
  float*  XWIOU = (float*)(ws + 0ull);             // 50.3MB  phase5->6
  float*  XWF   = (float*)(ws + 50331648ull);      // 16.8MB  phase5->6
  __half* XT    = (__half*)(ws + 67108864ull);     // 17.8MB  phase3->5
  float*  FCb   = (float*)(ws + 67108864ull);      //  8.4MB  phase6
  float*  IOUL  = (float*)(ws + 75497472ull);      // 12.6MB  phase6
  float*  H     = (float*)(ws + 88080384ull);      // 16.8MB  phase6
  __half* T     = (__half*)(ws + 88080384ull);     // 16.8MB  phase1->2 (over H)
  __half* HexS  = (__half*)(ws + 88080384ull);     // 16.8MB  phase3 (over T/H)
  float*  C     = (float*)(ws + 104857600ull);     // 16.8MB  phase6
  // packs live inside C region (dead before C written):
  __half* BTft  = (__half*)(ws + 104857600ull);    // 950,272
  __half* BTwhf = (__half*)(ws + 105807872ull);    // 1,048,576
  __half* BTwhb = (__half*)(ws + 106856448ull);    // 1,048,576
  __half* BTiou = (__half*)(ws + 107905024ull);    // 835,584
  __half* BTf   = (__half*)(ws + 108740608ull);    // 278,528
  __half* WBf   = (__half*)(ws + 109019136ull);    // 524,288
  __half* WBb   = (__half*)(ws + 109543424ull);    // 524,288
  unsigned int* FLG = (unsigned int*)(ws + 110198784ull);  // 16,384

  EmbArgs ea{tf, pos_ids, dep_ids, e1, e2, sdp, pos_tab, dep_tab, dist_tab, sdp_tab};

  // 0. weight packs + flag zero
  k_packB<<<dim3(912, 2), dim3(256), 0, stream>>>(W_ft, BTft, 512, 928);
  k_zft<<<dim3(32), dim3(256), 0, stream>>>(BTft);
  k_packB<<<dim3(512, 4), dim3(256), 0, stream>>>(Wih_f, BTwhf, 1024, 512);
  k_packB<<<dim3(512, 4), dim3(256), 0, stream>>>(Wih_b, BTwhb, 1024, 512);
  k_packB<<<dim3(544, 3), dim3(256), 0, stream>>>(W_iou, BTiou, 768, 544);
  k_packB<<<dim3(544, 1), dim3(256), 0, stream>>>(Wf_t, BTf, 256, 544);
  k_packWB<<<dim3(1024), dim3(256), 0, stream>>>(Whh_f, WBf);
  k_packWB<<<dim3(1024), dim3(256), 0, stream>>>(Whh_b, WBb);
  k_zero<<<dim3(16), dim3(256), 0, stream>>>(FLG, 4096);

  // 1. T = tanh(embed @ W_ft + b_ft)  [f16 out, embed fused]
  k_mgemm<<<dim3(4, 128), dim3(256), 0, stream>>>(
      nullptr, BTft, b_ft, (void*)T, 512, 928, 0, 1, 1, 1, ea);
  // 2. xW_f / xW_b  [f16 out, LSTM staging layout]
  k_mgemm<<<dim3(8, 128), dim3(256), 0, stream>>>(
      T, BTwhf, bl_f, (void*)XF, 1024, 512, 512, 0, 0, 2, ea);
  k_mgemm<<<dim3(8, 128), dim3(256), 0, stream>>>(
      T, BTwhb, bl_b, (void*)XB, 1024, 512, 512, 0, 0, 2, ea);
  // 3. BiLSTM -> XT cols [0,512)   (HexS overlays dead T)
  k_lstm3<<<dim3(16), dim3(256), 0, stream>>>(XF, XB, WBf, WBb, HexS, FLG, XT);
  // 4. dep_emb -> XT cols [512,544)
  k_depfill<<<dim3(2048), dim3(256), 0, stream>>>(dep_ids, dep_tab, XT);
  // 5. xWiou / xWf  [f32 out]
  k_mgemm<<<dim3(6, 128), dim3(256), 0, stream>>>(
      XT, BTiou, b_iou, (void*)XWIOU, 768, 544, 544, 0, 0, 0, ea);
  k_mgemm<<<dim3(2, 128), dim3(256), 0, stream>>>(
      XT, BTf, bf_t, (void*)XWF, 256, 544, 544, 0, 0, 0, ea);
  // 6. tree: leaves then levels bottom-up (exact vs 9 dense sweeps)
  k_leaves<<<dim3(8192), dim3(256), 0, stream>>>(XWIOU, H, C);
  const int plos[8] = {64, 32, 16, 8, 4, 2, 1, 0};
  const int lgs[8]  = {6, 5, 4, 3, 2, 1, 0, 0};
  for (int s = 0; s < 8; ++s) {
    int plo = plos[s], lg = lgs[s];
    int npar = 1 << lg;
    int Mch = 64 * 2 * npar;
    int Mp = 64 * npar;
    k_gemm<<<dim3(2, (Mch + 127) / 128), dim3(256), 0, stream>>>(
        H, Uf_t, nullptr, (void*)FCb, Mch, 256, 256, 0,
        1, 2 * plo, lg + 1, 2, heads, XWF, C);
    k_gemm<<<dim3(6, (Mp + 127) / 128), dim3(256), 0, stream>>>(
        H, U_iou, nullptr, (void*)IOUL, Mp, 768, 256, 0,
        2, plo, lg, 0, nullptr, nullptr, nullptr);
    k_update<<<dim3(Mp), dim3(256), 0, stream>>>(XWIOU, IOUL, FCb, H, C, plo, lg);
  }
  // 7. classifier
  k_classifier<<<dim3(64), dim3(256), 0, stream>>>(H, root, W1, b1, W2, b2,
                                                   (float*)d_out);
}